// Round 6
// baseline (92.904 us; speedup 1.0000x reference)
//
#include <hip/hip_runtime.h>
#include <hip/hip_bf16.h>

typedef unsigned int u32;
typedef unsigned short u16;
typedef unsigned char u8;
typedef _Float16 f16;
typedef __attribute__((ext_vector_type(2)))  _Float16 f16x2;
typedef __attribute__((ext_vector_type(8)))  _Float16 f16x8;
typedef __attribute__((ext_vector_type(16))) _Float16 f16x16;
typedef __attribute__((ext_vector_type(4))) float f32x4;

#define NSLOT   71
#define NCARD   71
#define ONEHOT  5041     // 71*71
#define INDIM   5048     // 71*71 + 7
#define D0      512
#define D1      256
#define D2      128
#define NACT    9

__device__ __forceinline__ u16 f2h_bits(float x) { f16 h = (f16)x; u16 r; __builtin_memcpy(&r, &h, 2); return r; }

// ---------------- prep: W0 -> f16, W1 -> W1T f16 (N x K), W2 -> W2T f16 ----------------
__global__ void prep_kernel(const float* __restrict__ W0, const float* __restrict__ W1,
                            const float* __restrict__ W2,
                            u16* __restrict__ W0h, u16* __restrict__ W1T, u16* __restrict__ W2T) {
    int i = blockIdx.x * 256 + threadIdx.x;
    const int n0 = INDIM * D0;      // 2,584,576
    const int n1 = D0 * D1;         // 131,072
    const int n2 = D1 * D2;         // 32,768
    if (i < n0) {
        W0h[i] = f2h_bits(W0[i]);
    } else if (i < n0 + n1) {
        int j = i - n0; int n = j >> 9, k = j & 511;     // W1T[n][k] = W1[k][n]
        W1T[j] = f2h_bits(W1[k * D1 + n]);
    } else if (i < n0 + n1 + n2) {
        int j = i - n0 - n1; int n = j >> 8, k = j & 255; // W2T[n][k] = W2[k][n]
        W2T[j] = f2h_bits(W2[k * D2 + n]);
    }
}

// Stage slot s's 71x128-col W0 slice into LDS (18432B incl. 1 garbage card row).
// 18 chunks of 1024B; wave w takes chunks w, w+8, w+16. Lane l -> card 4c+(l>>4),
// col byte (l&15)*16. LDS dest = chunk base + l*16 (global_load_lds lane rule).
__device__ __forceinline__ void stage_slice(const u16* __restrict__ W0h, int s, u16* lbuf,
                                            int wvid, int ln, int cbase) {
    for (int c = wvid; c < 18; c += 8) {
        size_t gelem = ((size_t)s * NCARD + c * 4 + (ln >> 4)) * D0 + cbase + (ln & 15) * 8;
        const u32* gp = (const u32*)(W0h + gelem);
        u32* lp = (u32*)(lbuf + c * 512);
        __builtin_amdgcn_global_load_lds((const __attribute__((address_space(1))) u32*)gp,
                                         (__attribute__((address_space(3))) u32*)lp,
                                         16, 0, 0);
    }
}

// ---------------- layer 0: LDS-staged gather-sum, ReLU, write h0 f16 ----------------
// grid: 512 blocks = (chunk 0..127 slow) x (ct 0..3 fast, XCD-aligned: R5 evidence).
// 128 rows/block, 512 threads = 64 rowgrp x 8 colgrp, 2 rows/thread, 2 blocks/CU.
// Per slot: stage next slice into LDS buf (s+1)&1 (async), gather this slot from
// buf s&1 via ds_read_b128 (LDS pipe 128B/cy vs L1 64B/cy). __syncthreads drains
// vmcnt -> staged slice complete; end-of-iter barrier also protects WAR on buffers.
__global__ __launch_bounds__(512)
void layer0_kernel(const int* __restrict__ sidx, const float* __restrict__ trump,
                   const float* __restrict__ b0, const u16* __restrict__ W0h,
                   u16* __restrict__ h0) {
    __shared__ __align__(16) u16 slice[2][72 * 128];   // 2 x 18432 B
    __shared__ u8 idxl[128 * NSLOT];                   // [row][slot]
    __shared__ float trl[128 * 7];                     // [row][t]
    const int tid = threadIdx.x;
    const int wvid = tid >> 6;               // wave 0..7
    const int ln = tid & 63;
    const int ct = blockIdx.x & 3;           // fast -> constant per XCD
    const int rbase = (blockIdx.x >> 2) * 128;
    const int cbase = ct * 128;

    stage_slice(W0h, 0, &slice[0][0], wvid, ln, cbase);   // slot 0 -> buf 0 (async)

    for (int i = tid; i < 128 * NSLOT; i += 512) {        // coalesced: i = r*71+s
        int v = sidx[rbase * NSLOT + i];
        v = v < 0 ? 0 : (v > NCARD - 1 ? NCARD - 1 : v);
        idxl[i] = (u8)v;
    }
    for (int i = tid; i < 128 * 7; i += 512)
        trl[i] = trump[rbase * 7 + i];

    const int rg = tid >> 3;                 // 0..63
    const int cg = tid & 7;                  // 0..7
    const int c0 = cbase + cg * 16;          // col offset in [0,512)

    __syncthreads();   // idxl/trl visible; slot-0 staging drained (vmcnt 0 before barrier)

    f16x16 acc[2];
    {   // init with b0 + trump tail (rows 5041..5047 of W0)
        f16x16 bias;
        #pragma unroll
        for (int j = 0; j < 16; ++j) bias[j] = (f16)b0[c0 + j];
        acc[0] = bias; acc[1] = bias;
        #pragma unroll
        for (int t = 0; t < 7; ++t) {
            f16x16 w16 = *(const f16x16*)(W0h + (size_t)(ONEHOT + t) * D0 + c0);
            acc[0] += w16 * (f16)trl[(rg * 2 + 0) * 7 + t];
            acc[1] += w16 * (f16)trl[(rg * 2 + 1) * 7 + t];
        }
    }

    for (int s = 0; s < NSLOT; ++s) {
        if (s + 1 < NSLOT)
            stage_slice(W0h, s + 1, &slice[(s + 1) & 1][0], wvid, ln, cbase);  // prefetch
        const u16* sl = &slice[s & 1][0];
        int card0 = idxl[(rg * 2 + 0) * NSLOT + s];
        int card1 = idxl[(rg * 2 + 1) * NSLOT + s];
        acc[0] += *(const f16x16*)(sl + card0 * 128 + cg * 16);   // 2x ds_read_b128
        acc[1] += *(const f16x16*)(sl + card1 * 128 + cg * 16);
        __syncthreads();   // staged s+1 complete (vmcnt drain); reads of buf s&1 done
    }

    const f16x16 zero = {};
    #pragma unroll
    for (int i = 0; i < 2; ++i) {
        int row = rbase + rg * 2 + i;
        f16x16 v = __builtin_elementwise_max(acc[i], zero);   // ReLU, packed
        uint4* dst = (uint4*)(h0 + (size_t)row * D0 + c0);
        dst[0] = ((const uint4*)&v)[0];
        dst[1] = ((const uint4*)&v)[1];
    }
}

// ---------------- layers 1,2,p fused: per-block 32 rows, MFMA 16x16x32 f16 ----------------
// grid: 512 blocks x 512 threads (8 waves).  LDS < 64KB.
__global__ __launch_bounds__(512)
void mlp_kernel(const u16* __restrict__ h0, const u16* __restrict__ W1T, const u16* __restrict__ W2T,
                const float* __restrict__ b1, const float* __restrict__ b2,
                const float* __restrict__ Wp, const float* __restrict__ bp,
                const int* __restrict__ legal, float* __restrict__ out) {
    __shared__ u16 Abuf[32 * 520];          // h0 tile, pad 8 (row 1040B)
    __shared__ u16 h1buf[32 * 264];         // pad 8 (528B)
    __shared__ u16 h2buf[32 * 136];         // pad 8 (272B)
    __shared__ float wpb[D2 * NACT + NACT]; // Wp + bp
    const int tid = threadIdx.x;
    const int r0 = blockIdx.x * 32;

    for (int i = tid; i < 2048; i += 512) {             // 32 rows x 64 uint4
        int r = i >> 6, g = i & 63;
        uint4 v = *(const uint4*)(h0 + (size_t)(r0 + r) * D0 + g * 8);
        *(uint4*)&Abuf[r * 520 + g * 8] = v;
    }
    for (int i = tid; i < D2 * NACT + NACT; i += 512)
        wpb[i] = (i < D2 * NACT) ? Wp[i] : bp[i - D2 * NACT];
    __syncthreads();

    const int w  = tid >> 6;     // wave 0..7
    const int l  = tid & 63;
    const int lc = l & 15;       // A row / B col / D col within 16-frag
    const int kg = l >> 4;       // 0..3

    // ---- layer 1: (32x512) @ (512x256), waves split N into 8 x 32 ----
    {
        const int n0 = w * 32;
        f32x4 a00 = {0.f,0.f,0.f,0.f}, a01 = a00, a10 = a00, a11 = a00;
        for (int kb = 0; kb < D0; kb += 32) {
            f16x8 av0 = *(const f16x8*)&Abuf[lc * 520 + kb + kg * 8];
            f16x8 av1 = *(const f16x8*)&Abuf[(lc + 16) * 520 + kb + kg * 8];
            f16x8 bv0 = *(const f16x8*)(W1T + (size_t)(n0 + lc) * D0 + kb + kg * 8);
            f16x8 bv1 = *(const f16x8*)(W1T + (size_t)(n0 + 16 + lc) * D0 + kb + kg * 8);
            a00 = __builtin_amdgcn_mfma_f32_16x16x32_f16(av0, bv0, a00, 0, 0, 0);
            a01 = __builtin_amdgcn_mfma_f32_16x16x32_f16(av0, bv1, a01, 0, 0, 0);
            a10 = __builtin_amdgcn_mfma_f32_16x16x32_f16(av1, bv0, a10, 0, 0, 0);
            a11 = __builtin_amdgcn_mfma_f32_16x16x32_f16(av1, bv1, a11, 0, 0, 0);
        }
        #pragma unroll
        for (int nb = 0; nb < 2; ++nb) {
            int col = n0 + nb * 16 + lc;
            float bias = b1[col];
            #pragma unroll
            for (int j = 0; j < 4; ++j) {
                f32x4 v0 = nb ? a01 : a00;
                f32x4 v1 = nb ? a11 : a10;
                h1buf[(kg * 4 + j) * 264 + col]        = f2h_bits(fmaxf(v0[j] + bias, 0.f));
                h1buf[(16 + kg * 4 + j) * 264 + col]   = f2h_bits(fmaxf(v1[j] + bias, 0.f));
            }
        }
    }
    __syncthreads();

    // ---- layer 2: (32x256) @ (256x128), waves split N into 8 x 16 ----
    {
        const int n0 = w * 16;
        f32x4 c0 = {0.f,0.f,0.f,0.f}, c1 = c0;
        for (int kb = 0; kb < D1; kb += 32) {
            f16x8 av0 = *(const f16x8*)&h1buf[lc * 264 + kb + kg * 8];
            f16x8 av1 = *(const f16x8*)&h1buf[(lc + 16) * 264 + kb + kg * 8];
            f16x8 bv  = *(const f16x8*)(W2T + (size_t)(n0 + lc) * D1 + kb + kg * 8);
            c0 = __builtin_amdgcn_mfma_f32_16x16x32_f16(av0, bv, c0, 0, 0, 0);
            c1 = __builtin_amdgcn_mfma_f32_16x16x32_f16(av1, bv, c1, 0, 0, 0);
        }
        int col = n0 + lc;
        float bias = b2[col];
        #pragma unroll
        for (int j = 0; j < 4; ++j) {
            h2buf[(kg * 4 + j) * 136 + col]      = f2h_bits(fmaxf(c0[j] + bias, 0.f));
            h2buf[(16 + kg * 4 + j) * 136 + col] = f2h_bits(fmaxf(c1[j] + bias, 0.f));
        }
    }
    __syncthreads();

    // ---- layer p + log_softmax: 128 threads, 4 threads per row (K split 4x32) ----
    if (tid < 128) {
        int r = tid >> 2, q = tid & 3;
        float part[NACT];
        #pragma unroll
        for (int a = 0; a < NACT; ++a) part[a] = 0.f;
        int kbase = q * 32;
        #pragma unroll
        for (int kk = 0; kk < 32; kk += 2) {
            u32 pr = *(const u32*)&h2buf[r * 136 + kbase + kk];
            f16x2 hp; __builtin_memcpy(&hp, &pr, 4);
            float x0 = (float)hp.x, x1 = (float)hp.y;
            #pragma unroll
            for (int a = 0; a < NACT; ++a)
                part[a] += x0 * wpb[(kbase + kk) * NACT + a] + x1 * wpb[(kbase + kk + 1) * NACT + a];
        }
        #pragma unroll
        for (int a = 0; a < NACT; ++a) {
            part[a] += __shfl_xor(part[a], 1, 64);
            part[a] += __shfl_xor(part[a], 2, 64);
        }
        if (q == 0) {
            int row = r0 + r;
            const int* mk = legal + (size_t)row * NACT;   // bool uploaded as 4-byte; nonzero = legal
            float lg[NACT]; float mx = -INFINITY;
            #pragma unroll
            for (int a = 0; a < NACT; ++a) {
                lg[a] = part[a] + wpb[D2 * NACT + a];
                if (mk[a] != 0 && lg[a] > mx) mx = lg[a];
            }
            float s = 0.f;
            #pragma unroll
            for (int a = 0; a < NACT; ++a) if (mk[a] != 0) s += __expf(lg[a] - mx);
            float lse = mx + __logf(s);
            #pragma unroll
            for (int a = 0; a < NACT; ++a)
                out[(size_t)row * NACT + a] = (mk[a] != 0) ? (lg[a] - lse) : -INFINITY;
        }
    }
}

extern "C" void kernel_launch(void* const* d_in, const int* in_sizes, int n_in,
                              void* d_out, int out_size, void* d_ws, size_t ws_size,
                              hipStream_t stream) {
    const int*   sidx  = (const int*)d_in[0];
    const float* trump = (const float*)d_in[1];
    const int*   legal = (const int*)d_in[2];
    const float* W0 = (const float*)d_in[3];
    const float* b0 = (const float*)d_in[4];
    const float* W1 = (const float*)d_in[5];
    const float* b1 = (const float*)d_in[6];
    const float* W2 = (const float*)d_in[7];
    const float* b2 = (const float*)d_in[8];
    const float* Wp = (const float*)d_in[9];
    const float* bp = (const float*)d_in[10];
    float* out = (float*)d_out;

    // ws layout (f16 elements): W0h | W1T | W2T | h0   -> 22.3 MB total
    u16* W0h  = (u16*)d_ws;
    u16* W1T  = W0h + (size_t)INDIM * D0;
    u16* W2T  = W1T + (size_t)D0 * D1;
    u16* h0   = W2T + (size_t)D1 * D2;

    const int total = INDIM * D0 + D0 * D1 + D1 * D2;   // 2,748,416
    prep_kernel<<<(total + 255) / 256, 256, 0, stream>>>(W0, W1, W2, W0h, W1T, W2T);
    layer0_kernel<<<512, 512, 0, stream>>>(sidx, trump, b0, W0h, h0);
    mlp_kernel<<<512, 512, 0, stream>>>(h0, W1T, W2T, b1, b2, Wp, bp, legal, out);
}

// Round 7
// 82.797 us; speedup vs baseline: 1.1221x; 1.1221x over previous
//
#include <hip/hip_runtime.h>
#include <hip/hip_bf16.h>

typedef unsigned int u32;
typedef unsigned short u16;
typedef unsigned char u8;
typedef _Float16 f16;
typedef __attribute__((ext_vector_type(2)))  _Float16 f16x2;
typedef __attribute__((ext_vector_type(8)))  _Float16 f16x8;
typedef __attribute__((ext_vector_type(16))) _Float16 f16x16;
typedef __attribute__((ext_vector_type(4))) float f32x4;

#define NSLOT   71
#define NCARD   71
#define ONEHOT  5041     // 71*71
#define INDIM   5048     // 71*71 + 7
#define D0      512
#define D1      256
#define D2      128
#define NACT    9

__device__ __forceinline__ u16 f2h_bits(float x) { f16 h = (f16)x; u16 r; __builtin_memcpy(&r, &h, 2); return r; }

// ---------------- prep: W0 -> f16, W1 -> W1T f16 (N x K), W2 -> W2T f16 ----------------
__global__ void prep_kernel(const float* __restrict__ W0, const float* __restrict__ W1,
                            const float* __restrict__ W2,
                            u16* __restrict__ W0h, u16* __restrict__ W1T, u16* __restrict__ W2T) {
    int i = blockIdx.x * 256 + threadIdx.x;
    const int n0 = INDIM * D0;      // 2,584,576
    const int n1 = D0 * D1;         // 131,072
    const int n2 = D1 * D2;         // 32,768
    if (i < n0) {
        W0h[i] = f2h_bits(W0[i]);
    } else if (i < n0 + n1) {
        int j = i - n0; int n = j >> 9, k = j & 511;     // W1T[n][k] = W1[k][n]
        W1T[j] = f2h_bits(W1[k * D1 + n]);
    } else if (i < n0 + n1 + n2) {
        int j = i - n0 - n1; int n = j >> 8, k = j & 255; // W2T[n][k] = W2[k][n]
        W2T[j] = f2h_bits(W2[k * D2 + n]);
    }
}

// ---------------- layer 0: direct L1 gather-sum + depth-2 software pipeline ----------------
// grid: 512 blocks = (chunk slow) x (ct = b&3 fast, XCD-aligned: R5 FETCH evidence).
// 128 rows/block, 512 threads = 64 rowgrp x 8 colgrp, 2 rows/thread, 2 blocks/CU.
// Registers pa/pb hold slots s+2/s+3 while s/s+1 are accumulated: 4 b128-pair loads
// in flight per wave (R5 ran VGPR=32, ~2 in flight -> 443cy/iter latency-bound).
__global__ __launch_bounds__(512)
void layer0_kernel(const int* __restrict__ sidx, const float* __restrict__ trump,
                   const float* __restrict__ b0, const u16* __restrict__ W0h,
                   u16* __restrict__ h0) {
    __shared__ u8 idxl[128 * NSLOT];     // [row][slot]
    __shared__ float trl[128 * 7];       // [row][t]
    const int tid = threadIdx.x;
    const int ct = blockIdx.x & 3;           // fast -> constant per XCD
    const int rbase = (blockIdx.x >> 2) * 128;

    for (int i = tid; i < 128 * NSLOT; i += 512) {      // coalesced: i = r*71+s
        int v = sidx[rbase * NSLOT + i];
        v = v < 0 ? 0 : (v > NCARD - 1 ? NCARD - 1 : v);
        idxl[i] = (u8)v;
    }
    for (int i = tid; i < 128 * 7; i += 512)
        trl[i] = trump[rbase * 7 + i];
    __syncthreads();

    const int rg = tid >> 3;                 // 0..63
    const int cg = tid & 7;                  // 0..7
    const int c0 = ct * 128 + cg * 16;       // col offset in [0,512)
    const u8* ix0 = &idxl[(rg * 2 + 0) * NSLOT];
    const u8* ix1 = &idxl[(rg * 2 + 1) * NSLOT];
    const u16* Wc = W0h + c0;                // column base

    f16x16 acc0, acc1;
    {   // init with b0 + trump tail (rows 5041..5047 of W0)
        f16x16 bias;
        #pragma unroll
        for (int j = 0; j < 16; ++j) bias[j] = (f16)b0[c0 + j];
        acc0 = bias; acc1 = bias;
        #pragma unroll
        for (int t = 0; t < 7; ++t) {
            f16x16 w16 = *(const f16x16*)(Wc + (size_t)(ONEHOT + t) * D0);
            acc0 += w16 * (f16)trl[(rg * 2 + 0) * 7 + t];
            acc1 += w16 * (f16)trl[(rg * 2 + 1) * 7 + t];
        }
    }

#define LD0(s) (*(const f16x16*)(Wc + ((size_t)(s) * NCARD + ix0[(s)]) * D0))
#define LD1(s) (*(const f16x16*)(Wc + ((size_t)(s) * NCARD + ix1[(s)]) * D0))

    f16x16 pa0 = LD0(0), pa1 = LD1(0);       // slot s   (even)
    f16x16 pb0 = LD0(1), pb1 = LD1(1);       // slot s+1 (odd)
    int s = 0;
    for (; s + 3 < NSLOT; s += 2) {          // exits with s = 68 (NSLOT = 71)
        acc0 += pa0; acc1 += pa1;
        pa0 = LD0(s + 2); pa1 = LD1(s + 2);
        acc0 += pb0; acc1 += pb1;
        pb0 = LD0(s + 3); pb1 = LD1(s + 3);
    }
    // slots 68 (pa), 69 (pb) staged; 70 not yet loaded
    acc0 += pa0; acc1 += pa1;
    pa0 = LD0(70); pa1 = LD1(70);
    acc0 += pb0; acc1 += pb1;
    acc0 += pa0; acc1 += pa1;
#undef LD0
#undef LD1

    const f16x16 zero = {};
    f16x16 v0 = __builtin_elementwise_max(acc0, zero);   // ReLU, packed
    f16x16 v1 = __builtin_elementwise_max(acc1, zero);
    uint4* dst0 = (uint4*)(h0 + (size_t)(rbase + rg * 2 + 0) * D0 + c0);
    uint4* dst1 = (uint4*)(h0 + (size_t)(rbase + rg * 2 + 1) * D0 + c0);
    dst0[0] = ((const uint4*)&v0)[0];
    dst0[1] = ((const uint4*)&v0)[1];
    dst1[0] = ((const uint4*)&v1)[0];
    dst1[1] = ((const uint4*)&v1)[1];
}

// ---------------- layers 1,2,p fused: per-block 32 rows, MFMA 16x16x32 f16 ----------------
// grid: 512 blocks x 512 threads (8 waves).  LDS < 64KB.
__global__ __launch_bounds__(512)
void mlp_kernel(const u16* __restrict__ h0, const u16* __restrict__ W1T, const u16* __restrict__ W2T,
                const float* __restrict__ b1, const float* __restrict__ b2,
                const float* __restrict__ Wp, const float* __restrict__ bp,
                const int* __restrict__ legal, float* __restrict__ out) {
    __shared__ u16 Abuf[32 * 520];          // h0 tile, pad 8 (row 1040B)
    __shared__ u16 h1buf[32 * 264];         // pad 8 (528B)
    __shared__ u16 h2buf[32 * 136];         // pad 8 (272B)
    __shared__ float wpb[D2 * NACT + NACT]; // Wp + bp
    const int tid = threadIdx.x;
    const int r0 = blockIdx.x * 32;

    for (int i = tid; i < 2048; i += 512) {             // 32 rows x 64 uint4
        int r = i >> 6, g = i & 63;
        uint4 v = *(const uint4*)(h0 + (size_t)(r0 + r) * D0 + g * 8);
        *(uint4*)&Abuf[r * 520 + g * 8] = v;
    }
    for (int i = tid; i < D2 * NACT + NACT; i += 512)
        wpb[i] = (i < D2 * NACT) ? Wp[i] : bp[i - D2 * NACT];
    __syncthreads();

    const int w  = tid >> 6;     // wave 0..7
    const int l  = tid & 63;
    const int lc = l & 15;       // A row / B col / D col within 16-frag
    const int kg = l >> 4;       // 0..3

    // ---- layer 1: (32x512) @ (512x256), waves split N into 8 x 32 ----
    {
        const int n0 = w * 32;
        f32x4 a00 = {0.f,0.f,0.f,0.f}, a01 = a00, a10 = a00, a11 = a00;
        for (int kb = 0; kb < D0; kb += 32) {
            f16x8 av0 = *(const f16x8*)&Abuf[lc * 520 + kb + kg * 8];
            f16x8 av1 = *(const f16x8*)&Abuf[(lc + 16) * 520 + kb + kg * 8];
            f16x8 bv0 = *(const f16x8*)(W1T + (size_t)(n0 + lc) * D0 + kb + kg * 8);
            f16x8 bv1 = *(const f16x8*)(W1T + (size_t)(n0 + 16 + lc) * D0 + kb + kg * 8);
            a00 = __builtin_amdgcn_mfma_f32_16x16x32_f16(av0, bv0, a00, 0, 0, 0);
            a01 = __builtin_amdgcn_mfma_f32_16x16x32_f16(av0, bv1, a01, 0, 0, 0);
            a10 = __builtin_amdgcn_mfma_f32_16x16x32_f16(av1, bv0, a10, 0, 0, 0);
            a11 = __builtin_amdgcn_mfma_f32_16x16x32_f16(av1, bv1, a11, 0, 0, 0);
        }
        #pragma unroll
        for (int nb = 0; nb < 2; ++nb) {
            int col = n0 + nb * 16 + lc;
            float bias = b1[col];
            #pragma unroll
            for (int j = 0; j < 4; ++j) {
                f32x4 v0 = nb ? a01 : a00;
                f32x4 v1 = nb ? a11 : a10;
                h1buf[(kg * 4 + j) * 264 + col]        = f2h_bits(fmaxf(v0[j] + bias, 0.f));
                h1buf[(16 + kg * 4 + j) * 264 + col]   = f2h_bits(fmaxf(v1[j] + bias, 0.f));
            }
        }
    }
    __syncthreads();

    // ---- layer 2: (32x256) @ (256x128), waves split N into 8 x 16 ----
    {
        const int n0 = w * 16;
        f32x4 c0 = {0.f,0.f,0.f,0.f}, c1 = c0;
        for (int kb = 0; kb < D1; kb += 32) {
            f16x8 av0 = *(const f16x8*)&h1buf[lc * 264 + kb + kg * 8];
            f16x8 av1 = *(const f16x8*)&h1buf[(lc + 16) * 264 + kb + kg * 8];
            f16x8 bv  = *(const f16x8*)(W2T + (size_t)(n0 + lc) * D1 + kb + kg * 8);
            c0 = __builtin_amdgcn_mfma_f32_16x16x32_f16(av0, bv, c0, 0, 0, 0);
            c1 = __builtin_amdgcn_mfma_f32_16x16x32_f16(av1, bv, c1, 0, 0, 0);
        }
        int col = n0 + lc;
        float bias = b2[col];
        #pragma unroll
        for (int j = 0; j < 4; ++j) {
            h2buf[(kg * 4 + j) * 136 + col]      = f2h_bits(fmaxf(c0[j] + bias, 0.f));
            h2buf[(16 + kg * 4 + j) * 136 + col] = f2h_bits(fmaxf(c1[j] + bias, 0.f));
        }
    }
    __syncthreads();

    // ---- layer p + log_softmax: 128 threads, 4 threads per row (K split 4x32) ----
    if (tid < 128) {
        int r = tid >> 2, q = tid & 3;
        float part[NACT];
        #pragma unroll
        for (int a = 0; a < NACT; ++a) part[a] = 0.f;
        int kbase = q * 32;
        #pragma unroll
        for (int kk = 0; kk < 32; kk += 2) {
            u32 pr = *(const u32*)&h2buf[r * 136 + kbase + kk];
            f16x2 hp; __builtin_memcpy(&hp, &pr, 4);
            float x0 = (float)hp.x, x1 = (float)hp.y;
            #pragma unroll
            for (int a = 0; a < NACT; ++a)
                part[a] += x0 * wpb[(kbase + kk) * NACT + a] + x1 * wpb[(kbase + kk + 1) * NACT + a];
        }
        #pragma unroll
        for (int a = 0; a < NACT; ++a) {
            part[a] += __shfl_xor(part[a], 1, 64);
            part[a] += __shfl_xor(part[a], 2, 64);
        }
        if (q == 0) {
            int row = r0 + r;
            const int* mk = legal + (size_t)row * NACT;   // bool uploaded as 4-byte; nonzero = legal
            float lg[NACT]; float mx = -INFINITY;
            #pragma unroll
            for (int a = 0; a < NACT; ++a) {
                lg[a] = part[a] + wpb[D2 * NACT + a];
                if (mk[a] != 0 && lg[a] > mx) mx = lg[a];
            }
            float s = 0.f;
            #pragma unroll
            for (int a = 0; a < NACT; ++a) if (mk[a] != 0) s += __expf(lg[a] - mx);
            float lse = mx + __logf(s);
            #pragma unroll
            for (int a = 0; a < NACT; ++a)
                out[(size_t)row * NACT + a] = (mk[a] != 0) ? (lg[a] - lse) : -INFINITY;
        }
    }
}

extern "C" void kernel_launch(void* const* d_in, const int* in_sizes, int n_in,
                              void* d_out, int out_size, void* d_ws, size_t ws_size,
                              hipStream_t stream) {
    const int*   sidx  = (const int*)d_in[0];
    const float* trump = (const float*)d_in[1];
    const int*   legal = (const int*)d_in[2];
    const float* W0 = (const float*)d_in[3];
    const float* b0 = (const float*)d_in[4];
    const float* W1 = (const float*)d_in[5];
    const float* b1 = (const float*)d_in[6];
    const float* W2 = (const float*)d_in[7];
    const float* b2 = (const float*)d_in[8];
    const float* Wp = (const float*)d_in[9];
    const float* bp = (const float*)d_in[10];
    float* out = (float*)d_out;

    // ws layout (f16 elements): W0h | W1T | W2T | h0   -> 22.3 MB total
    u16* W0h  = (u16*)d_ws;
    u16* W1T  = W0h + (size_t)INDIM * D0;
    u16* W2T  = W1T + (size_t)D0 * D1;
    u16* h0   = W2T + (size_t)D1 * D2;

    const int total = INDIM * D0 + D0 * D1 + D1 * D2;   // 2,748,416
    prep_kernel<<<(total + 255) / 256, 256, 0, stream>>>(W0, W1, W2, W0h, W1T, W2T);
    layer0_kernel<<<512, 512, 0, stream>>>(sidx, trump, b0, W0h, h0);
    mlp_kernel<<<512, 512, 0, stream>>>(h0, W1T, W2T, b1, b2, Wp, bp, legal, out);
}